// Round 1
// 509.547 us; speedup vs baseline: 1.0204x; 1.0204x over previous
//
#include <hip/hip_runtime.h>
#include <math.h>

#define Bn   16
#define Cn   256
#define Hn   128
#define Wn   128
#define HIDE 128
#define HW   (Hn * Wn)   // 16384

typedef __attribute__((ext_vector_type(4))) float f32x4;

// ---------------------------------------------------------------------------
// Kernel 1: per-(b,c) mean over H*W. One block per (b,c) plane.
// 256 threads, each loads 16 float4 (coalesced), wave+LDS reduce.
// Cached (allocating) loads on purpose: this pass warms the 256 MiB L3 with
// x so the scale pass can re-read it from LLC instead of HBM.
// ---------------------------------------------------------------------------
__global__ __launch_bounds__(256) void mean_kernel(const float* __restrict__ x,
                                                   float* __restrict__ y) {
    const int bc  = blockIdx.x;
    const int tid = threadIdx.x;
    const f32x4* xp = (const f32x4*)(x + (size_t)bc * HW);

    float sum = 0.f;
#pragma unroll
    for (int k = 0; k < HW / 4 / 256; ++k) {   // 16 iters, 16 independent loads
        f32x4 v = xp[tid + k * 256];
        sum += (v.x + v.y) + (v.z + v.w);
    }
    // wave(64)-level reduce
    for (int off = 32; off > 0; off >>= 1)
        sum += __shfl_down(sum, off, 64);

    __shared__ float ls[4];
    if ((tid & 63) == 0) ls[tid >> 6] = sum;
    __syncthreads();
    if (tid == 0) {
        float s = (ls[0] + ls[1]) + (ls[2] + ls[3]);
        y[bc] = s * (1.0f / (float)HW);
    }
}

// ---------------------------------------------------------------------------
// Kernel 2: the whole gate MLP for one batch row per block (16 blocks).
//   h = y @ w1.T          (256 -> 128)
//   s = softmax(w2*h)
//   t = relu(w3*(h*s + h @ A2))
//   gate = sigmoid(t @ w4.T)   (128 -> 256)
// ~1.3 MFLOP total — latency-bound, keep it simple and exact (expf).
// ---------------------------------------------------------------------------
__global__ __launch_bounds__(256) void gate_kernel(const float* __restrict__ y,
                                                   const float* __restrict__ w1,
                                                   const float* __restrict__ w2s,
                                                   const float* __restrict__ w3s,
                                                   const float* __restrict__ w4,
                                                   const float* __restrict__ A2,
                                                   float* __restrict__ gate) {
    const int b   = blockIdx.x;
    const int tid = threadIdx.x;

    __shared__ float sy[Cn];
    __shared__ float sh[HIDE];
    __shared__ float st[HIDE];
    __shared__ float red[2];

    sy[tid] = y[b * Cn + tid];
    __syncthreads();

    const float w2 = w2s[0];
    const float w3 = w3s[0];

    // h[j] = sum_c y[c] * w1[j][c]
    if (tid < HIDE) {
        float acc = 0.f;
        const float* wr = w1 + tid * Cn;
#pragma unroll 4
        for (int c = 0; c < Cn; ++c) acc = fmaf(sy[c], wr[c], acc);
        sh[tid] = acc;
    }
    __syncthreads();

    // softmax stats (serial on thread 0 — 256 iters, negligible)
    if (tid == 0) {
        float m = -1e30f;
        for (int j = 0; j < HIDE; ++j) m = fmaxf(m, w2 * sh[j]);
        float s = 0.f;
        for (int j = 0; j < HIDE; ++j) s += expf(w2 * sh[j] - m);
        red[0] = m;
        red[1] = s;
    }
    __syncthreads();
    const float m = red[0], denom = red[1];

    // t[j] = relu(w3 * (h[j]*s[j] + sum_k h[k]*A2[k][j]))
    if (tid < HIDE) {
        float sj  = expf(w2 * sh[tid] - m) / denom;
        float acc = sh[tid] * sj;
        for (int k = 0; k < HIDE; ++k) acc = fmaf(sh[k], A2[k * HIDE + tid], acc);
        float t = w3 * acc;
        st[tid] = t > 0.f ? t : 0.f;
    }
    __syncthreads();

    // gate[c] = sigmoid(sum_j t[j] * w4[c][j])
    {
        float acc = 0.f;
        const float* wr = w4 + tid * HIDE;
#pragma unroll 4
        for (int j = 0; j < HIDE; ++j) acc = fmaf(st[j], wr[j], acc);
        gate[b * Cn + tid] = 1.f / (1.f + expf(-acc));
    }
}

// ---------------------------------------------------------------------------
// Kernel 3: out[b,c,:,:] = x[b,c,:,:] * gate[b,c]. One block per plane.
// Cached loads for x (should hit L3, warmed by mean_kernel);
// NON-TEMPORAL stores for out: no write-allocate, so out streaming does not
// evict x from the 256 MiB LLC (x is exactly LLC-sized — write-allocate
// would evict precisely the planes we are about to read, LRU-pathological).
// ---------------------------------------------------------------------------
__global__ __launch_bounds__(256) void scale_kernel(const float* __restrict__ x,
                                                    const float* __restrict__ gate,
                                                    float* __restrict__ out) {
    const int bc  = blockIdx.x;
    const int tid = threadIdx.x;
    const float g = gate[bc];
    const f32x4* xp = (const f32x4*)(x   + (size_t)bc * HW);
    f32x4*       op = (f32x4*)      (out + (size_t)bc * HW);

#pragma unroll
    for (int k = 0; k < HW / 4 / 256; ++k) {   // 16 iters
        f32x4 v = xp[tid + k * 256];
        v *= g;
        __builtin_nontemporal_store(v, &op[tid + k * 256]);
    }
}

extern "C" void kernel_launch(void* const* d_in, const int* in_sizes, int n_in,
                              void* d_out, int out_size, void* d_ws, size_t ws_size,
                              hipStream_t stream) {
    const float* x  = (const float*)d_in[0];
    const float* w1 = (const float*)d_in[1];
    const float* w2 = (const float*)d_in[2];
    const float* w3 = (const float*)d_in[3];
    const float* w4 = (const float*)d_in[4];
    const float* A2 = (const float*)d_in[5];
    float* out = (float*)d_out;

    float* y    = (float*)d_ws;          // B*C = 4096 floats
    float* gate = y + Bn * Cn;           // B*C = 4096 floats

    mean_kernel <<<Bn * Cn, 256, 0, stream>>>(x, y);
    gate_kernel <<<Bn,      256, 0, stream>>>(y, w1, w2, w3, w4, A2, gate);
    scale_kernel<<<Bn * Cn, 256, 0, stream>>>(x, gate, out);
}